// Round 10
// baseline (1668.571 us; speedup 1.0000x reference)
//
#include <hip/hip_runtime.h>
#include <hip/hip_bf16.h>
#include <stdint.h>

#define T_STEPS 512
#define BATCH   128
#define IN      512
#define HID     1024
#define OUTN    256

typedef __bf16 bf16x8 __attribute__((ext_vector_type(8)));
typedef float  f32x4  __attribute__((ext_vector_type(4)));
typedef unsigned short us8 __attribute__((ext_vector_type(8)));
typedef unsigned int   ui4 __attribute__((ext_vector_type(4)));

__device__ __forceinline__ unsigned short f2bf(float f) {
    uint32_t u = __float_as_uint(f);
    uint32_t r = (u + 0x7fffu + ((u >> 16) & 1u)) >> 16;   // RNE
    return (unsigned short)r;
}

// Agent-coherent 16B load (bypass L1+L2, read at LLC). Early-clobber output so
// regalloc can never overlap dest with the address pair. Issue-only.
__device__ __forceinline__ ui4 ld_u128_agent(const void* p) {
    ui4 v;
    asm volatile("global_load_dwordx4 %0, %1, off sc0 sc1"
                 : "=&v"(v) : "v"(p) : "memory");
    return v;
}
// Plain 16B load, issue-pinned (prefetch; claimed by explicit vmcnt later).
__device__ __forceinline__ float4 ld_f128(const void* p) {
    float4 v;
    asm volatile("global_load_dwordx4 %0, %1, off"
                 : "=&v"(v) : "v"(p) : "memory");
    return v;
}

// Swizzled LDS fragment load: 16B at row*stride + (kbyte ^ ((row&7)<<4))
__device__ __forceinline__ bf16x8 ld_frag(const unsigned short* smem, int row, int kbyte, int rowstride) {
    int off = row * rowstride + (kbyte ^ ((row & 7) << 4));
    return *reinterpret_cast<const bf16x8*>(reinterpret_cast<const char*>(smem) + off);
}

// Intra-WG slice-readiness poll (LDS, cheap, no LLC traffic).
__device__ __forceinline__ void lds_wait(const unsigned* p, unsigned t) {
    while (__hip_atomic_load(p, __ATOMIC_RELAXED, __HIP_MEMORY_SCOPE_WORKGROUP) < t) { }
}

__global__ __launch_bounds__(320, 1) void rnn_persistent(
    const float* __restrict__ seqs, const float* __restrict__ W_ih,
    const float* __restrict__ W_hh, const float* __restrict__ b_ih,
    const float* __restrict__ b_hh, const float* __restrict__ W_fc,
    const float* __restrict__ b_fc, float* __restrict__ out,
    unsigned short* __restrict__ hbuf,   // [2 slots][8 groups][32 slices][1KB] slice-major
    float* __restrict__ hfinal,          // [128][1024] fp32
    unsigned int* __restrict__ flags)    // [8][32][16] 64B-padded, zeroed
{
    const int tid  = threadIdx.x;
    const int lane = tid & 63;
    const int wv   = tid >> 6;          // 0..3 workers (K-split), 4 = watcher
    const int wg   = blockIdx.x;
    const int g    = wg >> 5;           // batch group 0..7 (rows g*16..+15)
    const int w    = wg & 31;           // col slice (cols w*32..+31)
    const int gr0  = g * 16;
    const int c0   = w * 32;
    const int ln15 = lane & 15;
    const int lk   = lane >> 4;

    __shared__ unsigned short xtile[16 * 512];   // 16KB, swizzled bf16
    __shared__ float red[4][16][33];             // worker-wave partials (+1 pad)
    __shared__ float biasS[32];
    __shared__ unsigned ready[32];               // per-slice readiness watermark

    // ---- init: weight B-fragments into registers (worker waves only) ----
    bf16x8 wih[2][4];
    bf16x8 whh[2][8];
    if (wv < 4) {
        #pragma unroll
        for (int nt = 0; nt < 2; nt++) {
            const int j = c0 + nt * 16 + ln15;
            #pragma unroll
            for (int s = 0; s < 4; s++) {
                const int k = wv * 128 + s * 32 + lk * 8;
                const float* p = W_ih + j * IN + k;
                us8 u;
                #pragma unroll
                for (int e = 0; e < 8; e++) u[e] = f2bf(p[e]);
                wih[nt][s] = __builtin_bit_cast(bf16x8, u);
            }
            #pragma unroll
            for (int s = 0; s < 8; s++) {
                const int k = wv * 256 + s * 32 + lk * 8;
                const float* p = W_hh + j * HID + k;
                us8 u;
                #pragma unroll
                for (int e = 0; e < 8; e++) u[e] = f2bf(p[e]);
                whh[nt][s] = __builtin_bit_cast(bf16x8, u);
            }
        }
    }
    if (tid < 32) {
        biasS[tid] = b_ih[c0 + tid] + b_hh[c0 + tid];
        ready[tid] = 0u;
    }

    unsigned int* grp_flags = flags + g * 32 * 16;   // 64B-padded
    unsigned int* my_flag   = grp_flags + w * 16;

    // per-thread x chunk coords (16B chunks, 64 per row) — valid for tid<256
    const int xrow[4] = { (tid) >> 6, (tid + 256) >> 6, (tid + 512) >> 6, (tid + 768) >> 6 };
    const int xcol[4] = { (tid) & 63, (tid + 256) & 63, (tid + 512) & 63, (tid + 768) & 63 };

    // ---- prologue: x(0) load+convert -> xtile; issue x(1) prefetch ----
    us8 xbf[4];
    float4 xr[8];
    if (tid < 256) {
        const float* xsrc = seqs + (size_t)gr0 * IN;
        #pragma unroll
        for (int it = 0; it < 4; it++) {
            const float* s4 = xsrc + xrow[it] * IN + xcol[it] * 8;
            float4 a = *reinterpret_cast<const float4*>(s4);
            float4 b = *reinterpret_cast<const float4*>(s4 + 4);
            us8 u;
            u[0]=f2bf(a.x); u[1]=f2bf(a.y); u[2]=f2bf(a.z); u[3]=f2bf(a.w);
            u[4]=f2bf(b.x); u[5]=f2bf(b.y); u[6]=f2bf(b.z); u[7]=f2bf(b.w);
            xbf[it] = u;
        }
        #pragma unroll
        for (int it = 0; it < 4; it++) {
            const int off = xrow[it] * 1024 + ((xcol[it] * 16) ^ ((xrow[it] & 7) << 4));
            *reinterpret_cast<us8*>(reinterpret_cast<char*>(xtile) + off) = xbf[it];
        }
        const float* xn = seqs + (size_t)1 * (BATCH * IN) + (size_t)gr0 * IN;
        #pragma unroll
        for (int it = 0; it < 4; it++) {
            const float* s4 = xn + xrow[it] * IN + xcol[it] * 8;
            xr[2*it]   = ld_f128(s4);
            xr[2*it+1] = ld_f128(s4 + 4);
        }
    }
    __syncthreads();

    const size_t slotB = 8 * 32 * 1024;              // 256KB per ring slot
    char* hbase = reinterpret_cast<char*>(hbuf);
    const int loff = ln15 * 64 + lk * 16;            // lane offset within a 1KB slice

    for (int t = 0; t < T_STEPS; t++) {
        // 1: x-projection MFMAs from xtile (x(t)) — worker waves
        f32x4 acc0 = {0.f, 0.f, 0.f, 0.f};
        f32x4 acc1 = {0.f, 0.f, 0.f, 0.f};
        if (wv < 4) {
            const int kx0b = wv * 256;
            #pragma unroll
            for (int s = 0; s < 4; s++) {
                bf16x8 a = ld_frag(xtile, ln15, kx0b + s * 64 + lk * 16, 1024);
                acc0 = __builtin_amdgcn_mfma_f32_16x16x32_bf16(a, wih[0][s], acc0, 0, 0, 0);
                acc1 = __builtin_amdgcn_mfma_f32_16x16x32_bf16(a, wih[1][s], acc1, 0, 0, 0);
            }
        }

        // 2: claim x(t+1) (issued a full step ago) and convert
        asm volatile("s_waitcnt vmcnt(0)" ::: "memory");
        __builtin_amdgcn_sched_barrier(0);
        if (tid < 256) {
            #pragma unroll
            for (int it = 0; it < 4; it++) {
                float4 a = xr[2*it], b = xr[2*it+1];
                us8 u;
                u[0]=f2bf(a.x); u[1]=f2bf(a.y); u[2]=f2bf(a.z); u[3]=f2bf(a.w);
                u[4]=f2bf(b.x); u[5]=f2bf(b.y); u[6]=f2bf(b.z); u[7]=f2bf(b.w);
                xbf[it] = u;
            }
        }

        // 3: recurrence — watcher publishes slice readiness; workers pipeline
        if (t > 0) {
            if (wv == 4) {
                // WATCHER: spin the 32 group flags; publish ready[j]=t as each lands
                unsigned long long done = 0;
                const unsigned int* f = grp_flags + (lane & 31) * 16;
                for (;;) {
                    unsigned v = __hip_atomic_load(f, __ATOMIC_RELAXED, __HIP_MEMORY_SCOPE_AGENT);
                    unsigned long long m  = __ballot(v >= (unsigned)t);
                    unsigned long long nw = m & ~done;
                    if (lane < 32 && ((nw >> lane) & 1ull)) {
                        __hip_atomic_store(&ready[lane], (unsigned)t,
                                           __ATOMIC_RELAXED, __HIP_MEMORY_SCOPE_WORKGROUP);
                    }
                    done = m;
                    if (m == 0xFFFFFFFFFFFFFFFFull) break;
                }
            } else {
                // WORKERS: slice-granular load->MFMA pipeline over this wave's 8 slices
                const char* sb = hbase + (size_t)(t & 1) * slotB + g * 32768
                               + (wv * 8) * 1024 + loff;
                lds_wait(&ready[wv * 8], (unsigned)t);
                ui4 hA = ld_u128_agent(sb);
                ui4 hB;

#define STAGE(S, CUR, NXT)                                                          \
                lds_wait(&ready[wv * 8 + (S) + 1], (unsigned)t);                    \
                NXT = ld_u128_agent(sb + ((S) + 1) * 1024);                         \
                asm volatile("s_waitcnt vmcnt(1)" ::: "memory");                    \
                __builtin_amdgcn_sched_barrier(0);                                  \
                { bf16x8 a_ = __builtin_bit_cast(bf16x8, CUR);                      \
                  acc0 = __builtin_amdgcn_mfma_f32_16x16x32_bf16(a_, whh[0][S], acc0, 0, 0, 0); \
                  acc1 = __builtin_amdgcn_mfma_f32_16x16x32_bf16(a_, whh[1][S], acc1, 0, 0, 0); }

                STAGE(0, hA, hB)
                STAGE(1, hB, hA)
                STAGE(2, hA, hB)
                STAGE(3, hB, hA)
                STAGE(4, hA, hB)
                STAGE(5, hB, hA)
                STAGE(6, hA, hB)
#undef STAGE
                asm volatile("s_waitcnt vmcnt(0)" ::: "memory");
                __builtin_amdgcn_sched_barrier(0);
                {
                    bf16x8 a_ = __builtin_bit_cast(bf16x8, hB);
                    acc0 = __builtin_amdgcn_mfma_f32_16x16x32_bf16(a_, whh[0][7], acc0, 0, 0, 0);
                    acc1 = __builtin_amdgcn_mfma_f32_16x16x32_bf16(a_, whh[1][7], acc1, 0, 0, 0);
                }
            }
        }

        // 4: worker partials -> LDS
        if (wv < 4) {
            #pragma unroll
            for (int r = 0; r < 4; r++) {
                red[wv][lk * 4 + r][ln15]      = acc0[r];
                red[wv][lk * 4 + r][16 + ln15] = acc1[r];
            }
        }
        __syncthreads();   // B2: all slices consumed, partials staged

        // 5: reduce + bias + relu + store H_{t+1}
        if (tid < 256) {
            const int hrow = tid >> 4;          // 0..15
            const int co2  = (tid & 15) * 2;    // even col within slice
            float v0 = red[0][hrow][co2]   + red[1][hrow][co2]   + red[2][hrow][co2]   + red[3][hrow][co2]   + biasS[co2];
            float v1 = red[0][hrow][co2+1] + red[1][hrow][co2+1] + red[2][hrow][co2+1] + red[3][hrow][co2+1] + biasS[co2+1];
            v0 = fmaxf(v0, 0.0f);
            v1 = fmaxf(v1, 0.0f);
            if (t < T_STEPS - 1) {
                unsigned pack = (unsigned)f2bf(v0) | ((unsigned)f2bf(v1) << 16);
                unsigned* dst = reinterpret_cast<unsigned*>(
                    hbase + (size_t)((t + 1) & 1) * slotB + g * 32768 + w * 1024
                    + hrow * 64 + co2 * 2);
                __hip_atomic_store(dst, pack, __ATOMIC_RELAXED, __HIP_MEMORY_SCOPE_AGENT);
            } else {
                unsigned long long pack = ((unsigned long long)__float_as_uint(v1) << 32) | __float_as_uint(v0);
                unsigned long long* dst = reinterpret_cast<unsigned long long*>(
                    hfinal + (size_t)(gr0 + hrow) * HID + c0 + co2);
                __hip_atomic_store(dst, pack, __ATOMIC_RELAXED, __HIP_MEMORY_SCOPE_AGENT);
            }
        }

        // 6: drain stores (certify at LLC) -> xtile(x(t+1)) -> barrier -> flag
        asm volatile("s_waitcnt vmcnt(0)" ::: "memory");
        __builtin_amdgcn_sched_barrier(0);
        if (tid < 256) {
            #pragma unroll
            for (int it = 0; it < 4; it++) {
                const int off = xrow[it] * 1024 + ((xcol[it] * 16) ^ ((xrow[it] & 7) << 4));
                *reinterpret_cast<us8*>(reinterpret_cast<char*>(xtile) + off) = xbf[it];
            }
        }
        __syncthreads();   // B3: stores drained, xtile ready
        if (tid == 0) {
            __hip_atomic_store(my_flag, (unsigned)(t + 1), __ATOMIC_RELAXED, __HIP_MEMORY_SCOPE_AGENT);
        }

        // 7: issue x(t+2) prefetch — fully off-chain, claimed next step
        if (tid < 256) {
            const int tn = (t + 2 < T_STEPS) ? t + 2 : T_STEPS - 1;
            const float* xn = seqs + (size_t)tn * (BATCH * IN) + (size_t)gr0 * IN;
            #pragma unroll
            for (int it = 0; it < 4; it++) {
                const float* s4 = xn + xrow[it] * IN + xcol[it] * 8;
                xr[2*it]   = ld_f128(s4);
                xr[2*it+1] = ld_f128(s4 + 4);
            }
        }
    }

    // ---- final group barrier, then fused FC: out = hfinal @ W_fc^T + b_fc ----
    if (wv == 4 && lane < 32) {
        const unsigned int* f = grp_flags + lane * 16;
        while (__hip_atomic_load(f, __ATOMIC_RELAXED, __HIP_MEMORY_SCOPE_AGENT) < (unsigned)T_STEPS) {
            __builtin_amdgcn_s_sleep(1);
        }
    }
    __syncthreads();
    __threadfence();   // acquire: plain loads below see peers' hfinal

    {
        // WG computes out[gr0..gr0+15][w*8..w*8+7]; 2-way K-split over 256 threads
        if (tid < 256) {
            const int oi   = tid & 127;
            const int half = tid >> 7;
            const int brow = gr0 + (oi >> 3);
            const int o    = w * 8 + (oi & 7);
            const float* hv2 = hfinal + (size_t)brow * HID + half * 512;
            const float* wf  = W_fc  + (size_t)o * HID + half * 512;
            float sum = 0.f;
            #pragma unroll 4
            for (int k = 0; k < 512; k += 4) {
                float4 hh = *reinterpret_cast<const float4*>(hv2 + k);
                float4 ww = *reinterpret_cast<const float4*>(wf + k);
                sum += hh.x * ww.x + hh.y * ww.y + hh.z * ww.z + hh.w * ww.w;
            }
            float* redf = &red[0][0][0];
            redf[tid] = sum;
        }
        __syncthreads();
        if (tid < 128) {
            const int oi   = tid;
            const int brow = gr0 + (oi >> 3);
            const int o    = w * 8 + (oi & 7);
            float* redf = &red[0][0][0];
            out[(size_t)brow * OUTN + o] = redf[tid] + redf[tid + 128] + b_fc[o];
        }
    }
}

extern "C" void kernel_launch(void* const* d_in, const int* in_sizes, int n_in,
                              void* d_out, int out_size, void* d_ws, size_t ws_size,
                              hipStream_t stream) {
    const float* seqs = (const float*)d_in[0];
    const float* W_ih = (const float*)d_in[1];
    const float* W_hh = (const float*)d_in[2];
    const float* b_ih = (const float*)d_in[3];
    const float* b_hh = (const float*)d_in[4];
    const float* W_fc = (const float*)d_in[5];
    const float* b_fc = (const float*)d_in[6];
    float* out = (float*)d_out;

    char* ws = (char*)d_ws;
    unsigned short* hbuf   = (unsigned short*)ws;                 // 2*256KB slice-major ring
    float*          hfinal = (float*)(ws + 524288);               // 128*1024*4 = 524288 B
    unsigned int*   flags  = (unsigned int*)(ws + 1048576);       // 8*32*64 = 16384 B

    hipMemsetAsync(flags, 0, 8 * 32 * 64, stream);
    rnn_persistent<<<dim3(256), dim3(320), 0, stream>>>(
        seqs, W_ih, W_hh, b_ih, b_hh, W_fc, b_fc, out, hbuf, hfinal, flags);
}